// Round 18
// baseline (1401.241 us; speedup 1.0000x reference)
//
#include <hip/hip_runtime.h>
#include <hip/hip_bf16.h>

typedef __hip_bfloat16 bf16;
typedef __attribute__((ext_vector_type(8))) short short8;
typedef __attribute__((ext_vector_type(4))) float f32x4;

#define NB 64
#define NT 512
#define NC 192
#define NHEAD 2
#define NDH 96
#define NLAYER 6
#define NDFF 768
#define NW 4

constexpr int MROWS = NB * NT;            // 32768
constexpr size_t MC = (size_t)MROWS * NC; // 6291456
constexpr size_t MCB = MC * 4;
// 1/sqrt(96) * log2(e): folded into stored q so QK^T and rel-K land in exp2 domain
constexpr float QSC = 0.10206207261596575f * 1.4426950408889634f;

__device__ __forceinline__ float us2f(unsigned short x) { return __uint_as_float((unsigned)x << 16); }
__device__ __forceinline__ unsigned short f2b(float f) {
    bf16 h = __float2bfloat16(f);
    return *reinterpret_cast<unsigned short*>(&h);
}

// ---------------- weight conversion: pack into MFMA B-fragment tiles ----------------
__global__ __launch_bounds__(256) void cvt_frag_plain(const float* __restrict__ s, bf16* __restrict__ d,
                                                      int L, int N, int K) {
    int i = blockIdx.x * 256 + threadIdx.x;
    int total = L * (N / 16) * (K / 32) * 64;
    if (i >= total) return;
    int lane = i & 63;
    int tile = i >> 6;
    int nbk = K / 32;
    int kb = tile % nbk;
    int rest = tile / nbk;
    int nb = rest % (N / 16);
    int l = rest / (N / 16);
    int li = lane & 15, g = lane >> 4;
    const float* src = s + ((size_t)l * N + nb * 16 + li) * K + kb * 32 + g * 8;
    bf16* dst = d + (size_t)i * 8;
#pragma unroll
    for (int u = 0; u < 8; u++) dst[u] = __float2bfloat16(src[u]);
}
// conv: W[L][N][C][3] -> [L][3][N/16][C/32][64][8]
__global__ __launch_bounds__(256) void cvt_frag_conv(const float* __restrict__ s, bf16* __restrict__ d,
                                                     int L, int N, int C) {
    int i = blockIdx.x * 256 + threadIdx.x;
    int total = L * 3 * (N / 16) * (C / 32) * 64;
    if (i >= total) return;
    int lane = i & 63;
    int tile = i >> 6;
    int nbk = C / 32;
    int kb = tile % nbk;
    int rest = tile / nbk;
    int nb = rest % (N / 16);
    int rest2 = rest / (N / 16);
    int dk = rest2 % 3;
    int l = rest2 / 3;
    int li = lane & 15, g = lane >> 4;
    const float* src = s + (((size_t)l * N + nb * 16 + li) * C + kb * 32 + g * 8) * 3 + dk;
    bf16* dst = d + (size_t)i * 8;
#pragma unroll
    for (int u = 0; u < 8; u++) dst[u] = __float2bfloat16(src[u * 3]);
}

// ---------------- embedding (bf16 residual only) ----------------
__global__ __launch_bounds__(256) void embed_kernel(const int* __restrict__ tok,
                                                    const int* __restrict__ lens,
                                                    const float* __restrict__ emb,
                                                    bf16* __restrict__ xb) {
    int idx = blockIdx.x * 256 + threadIdx.x;
    if (idx >= (int)MC) return;
    int c = idx % NC;
    int m = idx / NC;
    int t = m % NT, b = m / NT;
    float v = emb[tok[m] * NC + c] * 13.856406460551018f; // sqrt(192)
    if (t >= lens[b]) v = 0.f;
    xb[idx] = __float2bfloat16(v);
}

// ---------------- plain MFMA GEMM (QKV / CONV1 / PROJ), frag-packed B from global ----------------
// 1-D grid (NBX*256), XCD-swizzled: all n-blocks of one m-panel land on the same XCD
// (bx=(d%(NBX*8))>>3, by=(d/(NBX*8))*8+(d&7); bijective since 256 % 8 == 0).
enum GMode { GM_QKV = 0, GM_CONV1 = 2, GM_PROJ = 4 };

template <int MODE, int NTOT, int KC, int TAPS, int BN>
__global__ __launch_bounds__(256) void gemm_mfma(const bf16* __restrict__ A,
                                                 const bf16* __restrict__ W,
                                                 const float* __restrict__ bias,
                                                 const int* __restrict__ lens,
                                                 float* __restrict__ of,
                                                 bf16* __restrict__ ob1,
                                                 bf16* __restrict__ ob2,
                                                 bf16* __restrict__ ob3) {
    constexpr int RA = (TAPS == 3) ? 130 : 128;
    constexpr int NBN = NTOT / 16;
    constexpr int NBK = KC / 32;
    constexpr int NSUB = BN / 16;
    constexpr int NBX = NTOT / BN;
    __shared__ unsigned short As[RA * 40];
    const int tid = threadIdx.x;
    const int w = tid >> 6, lane = tid & 63;
    const int g = lane >> 4, li = lane & 15;
    const int d = blockIdx.x;
    const int bx = (d % (NBX * 8)) >> 3;
    const int by = ((d / (NBX * 8)) << 3) + (d & 7);
    const int n0 = bx * BN;
    const int m0 = by * 128;
    const int b = m0 >> 9, t0 = m0 & 511;
    const int len = lens[b];
    const int nbBase = n0 >> 4;
    const unsigned short* Au = (const unsigned short*)A;
    const unsigned short* Wu = (const unsigned short*)W;

    f32x4 acc[2][NSUB];
#pragma unroll
    for (int a = 0; a < 2; a++)
#pragma unroll
        for (int s = 0; s < NSUB; s++) acc[a][s] = (f32x4){0.f, 0.f, 0.f, 0.f};

#pragma unroll 1
    for (int k0 = 0; k0 < KC; k0 += 32) {
        const int kb = k0 >> 5;
        __syncthreads();
        for (int c = tid; c < RA * 2; c += 256) {
            int i = c >> 1, hf = (c & 1) * 16;
            int t = t0 + i - (TAPS == 3 ? 1 : 0);
            bool valid = (t >= 0) && (t < NT);
            if constexpr (MODE == GM_CONV1) valid = valid && (t < len);
            short8 v0{}, v1{};
            if (valid) {
                const unsigned short* src = Au + ((size_t)(b * NT + t) * KC + k0 + hf);
                v0 = *(const short8*)src;
                v1 = *(const short8*)(src + 8);
            }
            *(short8*)&As[i * 40 + hf] = v0;
            *(short8*)&As[i * 40 + hf + 8] = v1;
        }
        __syncthreads();
        __builtin_amdgcn_s_setprio(1);
#pragma unroll
        for (int dk = 0; dk < TAPS; dk++) {
            short8 af0 = *(const short8*)&As[(w * 32 + li + dk) * 40 + g * 8];
            short8 af1 = *(const short8*)&As[(w * 32 + 16 + li + dk) * 40 + g * 8];
#pragma unroll
            for (int sub = 0; sub < NSUB; sub++) {
                short8 bfr = *(const short8*)(Wu +
                    ((((size_t)(dk * NBN + nbBase + sub)) * NBK + kb) << 9) + (lane << 3));
                acc[0][sub] = __builtin_amdgcn_mfma_f32_16x16x32_bf16(af0, bfr, acc[0][sub], 0, 0, 0);
                acc[1][sub] = __builtin_amdgcn_mfma_f32_16x16x32_bf16(af1, bfr, acc[1][sub], 0, 0, 0);
            }
        }
        __builtin_amdgcn_s_setprio(0);
    }

#pragma unroll
    for (int sub = 0; sub < NSUB; sub++) {
        int n = n0 + sub * 16 + li;
        float bv = bias[n];
#pragma unroll
        for (int a = 0; a < 2; a++) {
#pragma unroll
            for (int rr = 0; rr < 4; rr++) {
                int t = t0 + w * 32 + a * 16 + g * 4 + rr;
                size_t m = (size_t)(b * NT + t);
                float vv = acc[a][sub][rr] + bv;
                if constexpr (MODE == GM_QKV) {
                    int iw = n / NC;
                    int cc = n - iw * NC;
                    int hh = cc >= NDH ? 1 : 0;
                    int dch = cc - hh * NDH;
                    int bh = b * NHEAD + hh;
                    if (iw == 0) ob1[((size_t)bh * NT + t) * NDH + dch] = __float2bfloat16(vv * QSC);
                    else if (iw == 1) ob2[((size_t)bh * NT + t) * NDH + dch] = __float2bfloat16(vv);
                    else ob3[((size_t)bh * NDH + dch) * NT + t] = __float2bfloat16(vv); // V^T
                } else if constexpr (MODE == GM_CONV1) {
                    vv = vv > 0.f ? vv : 0.f;
                    if (t >= len) vv = 0.f;
                    ob1[m * NDFF + n] = __float2bfloat16(vv);
                } else { // GM_PROJ
                    if (t >= len) vv = 0.f;
                    int half = n >= 192 ? 1 : 0;
                    int cc = n - half * 192;
                    of[(size_t)(half + 1) * MC + ((size_t)b * NC + cc) * NT + t] = vv;
                }
            }
        }
    }
}

// ---------------- fused GEMM + residual + LayerNorm (OPROJ / CONV2), bf16 residual ----------------
// FINAL: additionally writes the masked transposed f32 x to `of` (fuses xpose_kernel).
template <int KC, int TAPS, bool MASKY, int BM, bool FINAL>
__global__ __launch_bounds__(512, 4) void gemm_ln(const bf16* __restrict__ A,
                                                  const bf16* __restrict__ W,
                                                  const float* __restrict__ bias,
                                                  const int* __restrict__ lens,
                                                  const float* __restrict__ lng,
                                                  const float* __restrict__ lnb,
                                                  bf16* __restrict__ xb,
                                                  float* __restrict__ of) {
    constexpr int RA = BM + ((TAPS == 3) ? 2 : 0);
    constexpr int NSTEP = KC / 32;
    constexpr int NBN = 12; // 192/16
    constexpr int NBK = KC / 32;
    constexpr int AR = BM / 32;
    __shared__ unsigned short As[RA * 40];
    __shared__ float rsm[BM][4];
    __shared__ float rsq[BM][4];
    const int tid = threadIdx.x;
    const int lane = tid & 63;
    const int g = lane >> 4, li = lane & 15;
    const int w = tid >> 6;
    const int wr = w & 1, wc = w >> 1;
    const int m0 = blockIdx.x * BM;
    const int b = m0 >> 9, t0 = m0 & 511;
    const int len = lens[b];
    const unsigned short* Au = (const unsigned short*)A;
    const unsigned short* Wu = (const unsigned short*)W;
    unsigned short* Xu = (unsigned short*)xb;

    const int ai = tid >> 1, ahf = (tid & 1) * 16;
    const int at = t0 + ai - (TAPS == 3 ? 1 : 0);
    const bool aon = (tid < RA * 2);
    const bool avalid = aon && (at >= 0) && (at < NT);

    short8 ra0{}, ra1{};
    short8 bcur[TAPS][3], bnxt[TAPS][3];

    f32x4 acc[AR][3];
#pragma unroll
    for (int ar = 0; ar < AR; ar++)
#pragma unroll
        for (int sub = 0; sub < 3; sub++) acc[ar][sub] = (f32x4){0.f, 0.f, 0.f, 0.f};

    if (avalid) {
        const unsigned short* src = Au + ((size_t)(b * NT + at) * KC + 0 + ahf);
        ra0 = *(const short8*)src;
        ra1 = *(const short8*)(src + 8);
    }
#pragma unroll
    for (int dk = 0; dk < TAPS; dk++)
#pragma unroll
        for (int sub = 0; sub < 3; sub++)
            bcur[dk][sub] = *(const short8*)(Wu +
                ((((size_t)(dk * NBN + wc * 3 + sub)) * NBK) << 9) + (lane << 3));
    if (aon) {
        short8 z{};
        *(short8*)&As[ai * 40 + ahf] = avalid ? ra0 : z;
        *(short8*)&As[ai * 40 + ahf + 8] = avalid ? ra1 : z;
    }

#pragma unroll 1
    for (int s = 0; s < NSTEP; s++) {
        __syncthreads();
        if (s + 1 < NSTEP) {
            int k0 = (s + 1) * 32;
            if (avalid) {
                const unsigned short* src = Au + ((size_t)(b * NT + at) * KC + k0 + ahf);
                ra0 = *(const short8*)src;
                ra1 = *(const short8*)(src + 8);
            }
#pragma unroll
            for (int dk = 0; dk < TAPS; dk++)
#pragma unroll
                for (int sub = 0; sub < 3; sub++)
                    bnxt[dk][sub] = *(const short8*)(Wu +
                        ((((size_t)(dk * NBN + wc * 3 + sub)) * NBK + (s + 1)) << 9) + (lane << 3));
        }
        __builtin_amdgcn_s_setprio(1);
#pragma unroll
        for (int dk = 0; dk < TAPS; dk++) {
            short8 af[AR];
#pragma unroll
            for (int ar = 0; ar < AR; ar++)
                af[ar] = *(const short8*)&As[(wr * (BM / 2) + ar * 16 + li + dk) * 40 + g * 8];
#pragma unroll
            for (int sub = 0; sub < 3; sub++) {
#pragma unroll
                for (int ar = 0; ar < AR; ar++)
                    acc[ar][sub] = __builtin_amdgcn_mfma_f32_16x16x32_bf16(af[ar], bcur[dk][sub], acc[ar][sub], 0, 0, 0);
            }
        }
        __builtin_amdgcn_s_setprio(0);
        __syncthreads();
        if (s + 1 < NSTEP) {
            if (aon) {
                short8 z{};
                *(short8*)&As[ai * 40 + ahf] = avalid ? ra0 : z;
                *(short8*)&As[ai * 40 + ahf + 8] = avalid ? ra1 : z;
            }
#pragma unroll
            for (int dk = 0; dk < TAPS; dk++)
#pragma unroll
                for (int sub = 0; sub < 3; sub++) bcur[dk][sub] = bnxt[dk][sub];
        }
    }

    float biasv[3], gv[3], bbv[3];
#pragma unroll
    for (int sub = 0; sub < 3; sub++) {
        int n = wc * 48 + sub * 16 + li;
        biasv[sub] = bias[n];
        gv[sub] = lng[n];
        bbv[sub] = lnb[n];
    }
    float psm[AR][4], psq[AR][4];
#pragma unroll
    for (int ar = 0; ar < AR; ar++) {
#pragma unroll
        for (int rr = 0; rr < 4; rr++) {
            int r = wr * (BM / 2) + ar * 16 + 4 * g + rr;
            int t = t0 + r;
            size_t m = (size_t)(b * NT + t);
            float sm = 0.f, sq = 0.f;
#pragma unroll
            for (int sub = 0; sub < 3; sub++) {
                int n = wc * 48 + sub * 16 + li;
                float y = acc[ar][sub][rr] + biasv[sub];
                if (MASKY && t >= len) y = 0.f;
                float rres = y + us2f(Xu[m * NC + n]);
                acc[ar][sub][rr] = rres;
                sm += rres;
                sq += rres * rres;
            }
            psm[ar][rr] = sm;
            psq[ar][rr] = sq;
        }
    }
#pragma unroll
    for (int off = 1; off < 16; off <<= 1) {
#pragma unroll
        for (int ar = 0; ar < AR; ar++)
#pragma unroll
            for (int rr = 0; rr < 4; rr++) {
                psm[ar][rr] += __shfl_xor(psm[ar][rr], off);
                psq[ar][rr] += __shfl_xor(psq[ar][rr], off);
            }
    }
    if (li == 0) {
#pragma unroll
        for (int ar = 0; ar < AR; ar++)
#pragma unroll
            for (int rr = 0; rr < 4; rr++) {
                int r = wr * (BM / 2) + ar * 16 + 4 * g + rr;
                rsm[r][wc] = psm[ar][rr];
                rsq[r][wc] = psq[ar][rr];
            }
    }
    __syncthreads();
#pragma unroll
    for (int ar = 0; ar < AR; ar++) {
#pragma unroll
        for (int rr = 0; rr < 4; rr++) {
            int r = wr * (BM / 2) + ar * 16 + 4 * g + rr;
            int t = t0 + r;
            size_t m = (size_t)(b * NT + t);
            float sm = rsm[r][0] + rsm[r][1] + rsm[r][2] + rsm[r][3];
            float sq = rsq[r][0] + rsq[r][1] + rsq[r][2] + rsq[r][3];
            float mu = sm * (1.f / NC);
            float var = fmaxf(sq * (1.f / NC) - mu * mu, 0.f);
            float rs = rsqrtf(var + 1e-5f);
#pragma unroll
            for (int sub = 0; sub < 3; sub++) {
                int n = wc * 48 + sub * 16 + li;
                float o = (acc[ar][sub][rr] - mu) * rs * gv[sub] + bbv[sub];
                Xu[m * NC + n] = f2b(o);
                if (FINAL) of[((size_t)b * NC + n) * NT + t] = (t < len) ? o : 0.f;
            }
        }
    }
}

// ---------------- MFMA flash attention v7: ones-column row-sum, lazy rmax reduce ----------------
__global__ __launch_bounds__(256, 4) void attn_mfma(const bf16* __restrict__ q,
                                                    const bf16* __restrict__ k,
                                                    const bf16* __restrict__ v,
                                                    const float* __restrict__ relk,
                                                    const float* __restrict__ relv,
                                                    const int* __restrict__ lens,
                                                    bf16* __restrict__ o) {
    __shared__ __align__(16) char pool[40448];
    unsigned short* Kt = (unsigned short*)pool;              // [64][104]
    unsigned short* Vt = (unsigned short*)(pool + 13312);    // [96][72]
    unsigned short* Pt = (unsigned short*)(pool + 27136);    // [4][16][72]
    unsigned short* Pb = (unsigned short*)(pool + 36352);    // [4][16][32]
    unsigned short* Qt = (unsigned short*)pool;              // prologue alias [64][104]
    unsigned short* Rk = (unsigned short*)(pool + 13312);    // prologue alias [16][104]

    const int bh = blockIdx.x, qt = blockIdx.y;
    const int b = bh >> 1, h = bh & 1;
    const int q0 = qt * 64;
    const int tid = threadIdx.x;
    const int w = tid >> 6, lane = tid & 63;
    const int g = lane >> 4, li = lane & 15;
    const int len = lens[b];
    const bool anymask = (len < NT);

    const unsigned short* qg = (const unsigned short*)q + (size_t)bh * NT * NDH;
    const unsigned short* kg = (const unsigned short*)k + (size_t)bh * NT * NDH;
    const unsigned short* vg = (const unsigned short*)v + (size_t)bh * NDH * NT; // V^T [96][512]

    // ---- prologue ----
    for (int c = tid; c < 64 * 12; c += 256) {
        int r = c / 12, seg = (c % 12) * 8;
        *(short8*)&Qt[r * 104 + seg] = *(const short8*)(qg + (size_t)(q0 + r) * NDH + seg);
    }
    for (int c = tid; c < 16 * 96; c += 256) {
        int dd = c / 96, d = c - (c / 96) * 96;
        Rk[dd * 104 + d] = (dd < 9) ? f2b(relk[dd * 96 + d]) : (unsigned short)0;
    }
    for (int c = tid; c < 4 * 16 * 32; c += 256) Pb[c] = 0;
    __syncthreads();

    // racc[rr] at lane (g,li) = Rt[4g+rr][li]  (q already scaled by QSC -> exp2 domain)
    f32x4 racc = (f32x4){0.f, 0.f, 0.f, 0.f};
    short8 qf[3];
#pragma unroll
    for (int kk = 0; kk < 3; kk++) {
        qf[kk] = *(const short8*)&Qt[(w * 16 + li) * 104 + kk * 32 + g * 8];
        short8 bfr = *(const short8*)&Rk[li * 104 + kk * 32 + g * 8];
        racc = __builtin_amdgcn_mfma_f32_16x16x32_bf16(qf[kk], bfr, racc, 0, 0, 0);
    }
    short8 rvf[6];
#pragma unroll
    for (int ds = 0; ds < 6; ds++) {
#pragma unroll
        for (int i = 0; i < 8; i++) {
            int j = g * 8 + i;
            int d = ds * 16 + li;
            unsigned short u = (j < 9) ? f2b(relv[j * 96 + d]) : (unsigned short)0;
            rvf[ds][i] = (short)u;
        }
    }
    // ones-column B fragment: B[k][0]=1 -> Oa[6] accumulates row sums of P
    short8 bones;
#pragma unroll
    for (int i = 0; i < 8; i++) bones[i] = (li == 0) ? (short)0x3F80 : (short)0;
    __syncthreads();

    float m_run[4];
    f32x4 Oa[7];
#pragma unroll
    for (int rr = 0; rr < 4; rr++) m_run[rr] = -1e30f;
#pragma unroll
    for (int ds = 0; ds < 7; ds++) Oa[ds] = (f32x4){0.f, 0.f, 0.f, 0.f};

    const int wrow0 = q0 + w * 16; // wave's first q-row

    for (int s0 = 0; s0 < NT; s0 += 64) {
        for (int c = tid; c < 64 * 12; c += 256) {
            int ss = c / 12, seg = (c % 12) * 8;
            *(short8*)&Kt[ss * 104 + seg] = *(const short8*)(kg + (size_t)(s0 + ss) * NDH + seg);
        }
        for (int c = tid; c < 96 * 8; c += 256) {
            int d = c >> 3, seg = (c & 7) * 8;
            *(short8*)&Vt[d * 72 + seg] = *(const short8*)(vg + (size_t)d * NT + s0 + seg);
        }
        __syncthreads();

        // wave-uniform: does the +/-4 rel band intersect this s-tile for this wave's rows?
        const bool band = (s0 <= wrow0 + 15 + NW) && (s0 + 63 >= wrow0 - NW);

        // ---- S' = (Q*QSC) K^T  (exp2 domain) ----
        f32x4 acc[4];
#pragma unroll
        for (int sub = 0; sub < 4; sub++) acc[sub] = (f32x4){0.f, 0.f, 0.f, 0.f};
        __builtin_amdgcn_s_setprio(1);
#pragma unroll
        for (int kk = 0; kk < 3; kk++) {
#pragma unroll
            for (int sub = 0; sub < 4; sub++) {
                short8 bfr = *(const short8*)&Kt[(sub * 16 + li) * 104 + kk * 32 + g * 8];
                acc[sub] = __builtin_amdgcn_mfma_f32_16x16x32_bf16(qf[kk], bfr, acc[sub], 0, 0, 0);
            }
        }
        __builtin_amdgcn_s_setprio(0);

        // ---- rel-K band (only on intersecting tiles) ----
        if (band) {
#pragma unroll
            for (int sub = 0; sub < 4; sub++) {
#pragma unroll
                for (int rr = 0; rr < 4; rr++) {
                    int scol = s0 + sub * 16 + li;
                    int qrow = wrow0 + 4 * g + rr;
                    int dd = scol - qrow;
                    float rv = __shfl(racc[rr], g * 16 + dd + NW);
                    if (dd >= -NW && dd <= NW) acc[sub][rr] += rv;
                }
            }
        }
        // ---- mask ----
        if (anymask) {
#pragma unroll
            for (int sub = 0; sub < 4; sub++) {
#pragma unroll
                for (int rr = 0; rr < 4; rr++) {
                    int scol = s0 + sub * 16 + li;
                    int qrow = wrow0 + 4 * g + rr;
                    if (scol >= len || qrow >= len) acc[sub][rr] -= 14427.0f; // -10000*log2(e)
                }
            }
        }
        // ---- per-thread row maxima; cross-lane reduce only if rescale needed ----
        float pmr[4];
#pragma unroll
        for (int rr = 0; rr < 4; rr++) {
            pmr[rr] = fmaxf(fmaxf(acc[0][rr], acc[1][rr]), fmaxf(acc[2][rr], acc[3][rr]));
        }
        float growth = fmaxf(fmaxf(pmr[0] - m_run[0], pmr[1] - m_run[1]),
                             fmaxf(pmr[2] - m_run[2], pmr[3] - m_run[3]));
        if (__any(growth > 11.54f)) { // 8 * log2(e)
#pragma unroll
            for (int off = 1; off < 16; off <<= 1)
#pragma unroll
                for (int rr = 0; rr < 4; rr++) pmr[rr] = fmaxf(pmr[rr], __shfl_xor(pmr[rr], off));
#pragma unroll
            for (int rr = 0; rr < 4; rr++) {
                float mn = fmaxf(m_run[rr], pmr[rr]);
                float scf = exp2f(m_run[rr] - mn);
                m_run[rr] = mn;
#pragma unroll
                for (int ds = 0; ds < 7; ds++) Oa[ds][rr] *= scf;
            }
        }
#pragma unroll
        for (int sub = 0; sub < 4; sub++)
#pragma unroll
            for (int rr = 0; rr < 4; rr++)
                acc[sub][rr] = exp2f(acc[sub][rr] - m_run[rr]);

        // ---- P -> LDS (per-wave) ----
#pragma unroll
        for (int sub = 0; sub < 4; sub++)
#pragma unroll
            for (int rr = 0; rr < 4; rr++)
                Pt[w * 1152 + (4 * g + rr) * 72 + sub * 16 + li] = f2b(acc[sub][rr]);

        // ---- O += P V ; Oa[6] += P . ones (row sums) ----
        __builtin_amdgcn_s_setprio(1);
#pragma unroll
        for (int kk = 0; kk < 2; kk++) {
            short8 pa = *(const short8*)&Pt[w * 1152 + li * 72 + kk * 32 + g * 8];
#pragma unroll
            for (int ds = 0; ds < 6; ds++) {
                short8 bv = *(const short8*)&Vt[(ds * 16 + li) * 72 + kk * 32 + g * 8];
                Oa[ds] = __builtin_amdgcn_mfma_f32_16x16x32_bf16(pa, bv, Oa[ds], 0, 0, 0);
            }
            Oa[6] = __builtin_amdgcn_mfma_f32_16x16x32_bf16(pa, bones, Oa[6], 0, 0, 0);
        }
        __builtin_amdgcn_s_setprio(0);

        // ---- rel-V band via MFMA (only on intersecting tiles) ----
        if (band) {
            for (int j = g; j < 9; j += 4) { // r = li, j in {g, g+4, g+8} covers 16x9
                int u = wrow0 + li + j - NW - s0;
                unsigned short pv_ = (u >= 0 && u < 64) ? Pt[w * 1152 + li * 72 + u] : (unsigned short)0;
                Pb[w * 512 + li * 32 + j] = pv_;
            }
            short8 pband = *(const short8*)&Pb[w * 512 + li * 32 + g * 8];
#pragma unroll
            for (int ds = 0; ds < 6; ds++)
                Oa[ds] = __builtin_amdgcn_mfma_f32_16x16x32_bf16(pband, rvf[ds], Oa[ds], 0, 0, 0);
        }
        __syncthreads();
    }

    // l for row 4g+rr lives in Oa[6][rr] at lane g*16 (col 0)
    float invl[4];
#pragma unroll
    for (int rr = 0; rr < 4; rr++) invl[rr] = 1.f / __shfl(Oa[6][rr], lane & 48);
#pragma unroll
    for (int ds = 0; ds < 6; ds++)
#pragma unroll
        for (int rr = 0; rr < 4; rr++) {
            int qrow = wrow0 + 4 * g + rr;
            o[((size_t)(b * NT + qrow)) * NC + h * 96 + ds * 16 + li] =
                __float2bfloat16(Oa[ds][rr] * invl[rr]);
        }
}

__global__ __launch_bounds__(256) void mask_kernel(const int* __restrict__ lens, float* __restrict__ out) {
    int idx = blockIdx.x * 256 + threadIdx.x;
    if (idx >= NB * NT) return;
    int t = idx % NT;
    int b = idx / NT;
    out[idx] = (t < lens[b]) ? 1.f : 0.f;
}

extern "C" void kernel_launch(void* const* d_in, const int* in_sizes, int n_in,
                              void* d_out, int out_size, void* d_ws, size_t ws_size,
                              hipStream_t stream) {
    (void)in_sizes; (void)n_in; (void)out_size; (void)ws_size;
    const int* tok = (const int*)d_in[0];
    const int* lens = (const int*)d_in[1];
    const float* emb = (const float*)d_in[2];
    const float* wqkv = (const float*)d_in[3];
    const float* bqkv = (const float*)d_in[4];
    const float* wo = (const float*)d_in[5];
    const float* bo = (const float*)d_in[6];
    const float* relk = (const float*)d_in[7];
    const float* relv = (const float*)d_in[8];
    const float* ln1g = (const float*)d_in[9];
    const float* ln1b = (const float*)d_in[10];
    const float* ln2g = (const float*)d_in[11];
    const float* ln2b = (const float*)d_in[12];
    const float* fw1 = (const float*)d_in[13];
    const float* fb1 = (const float*)d_in[14];
    const float* fw2 = (const float*)d_in[15];
    const float* fb2 = (const float*)d_in[16];
    const float* pw = (const float*)d_in[17];
    const float* pb = (const float*)d_in[18];
    float* out = (float*)d_out;

    char* wsb = (char*)d_ws;
    bf16* xb = (bf16*)(wsb + 2 * MCB);             // bf16 [M][C] residual carrier
    bf16* qb = (bf16*)(wsb + 2 * MCB + MCB / 2);   // bf16 [BH][T][DH] (scaled by QSC)
    bf16* kb = qb + MC;
    bf16* vb = kb + MC;                            // stored transposed: [BH][DH][T]
    bf16* ob = vb + MC;
    bf16* hB = qb;                                 // alias: bf16 [M][DFF] over qb..ob
    bf16* pwqkv = ob + MC;                         // frag-packed weights
    bf16* pwo = pwqkv + (size_t)NLAYER * 3 * NC * NC;
    bf16* pw1 = pwo + (size_t)NLAYER * NC * NC;
    bf16* pw2 = pw1 + (size_t)NLAYER * 3 * NDFF * NC;
    bf16* pproj = pw2 + (size_t)NLAYER * 3 * NC * NDFF;

    {
        int n1 = NLAYER * 36 * 6 * 64;      // qkv: N=576,K=192
        cvt_frag_plain<<<(n1 + 255) / 256, 256, 0, stream>>>(wqkv, pwqkv, NLAYER, 576, 192);
        int n2 = NLAYER * 12 * 6 * 64;      // wo: N=192,K=192
        cvt_frag_plain<<<(n2 + 255) / 256, 256, 0, stream>>>(wo, pwo, NLAYER, 192, 192);
        int n3 = 1 * 24 * 6 * 64;           // proj: N=384,K=192
        cvt_frag_plain<<<(n3 + 255) / 256, 256, 0, stream>>>(pw, pproj, 1, 384, 192);
        int n4 = NLAYER * 3 * 48 * 6 * 64;  // conv1: N=768,C=192
        cvt_frag_conv<<<(n4 + 255) / 256, 256, 0, stream>>>(fw1, pw1, NLAYER, 768, 192);
        int n5 = NLAYER * 3 * 12 * 24 * 64; // conv2: N=192,C=768
        cvt_frag_conv<<<(n5 + 255) / 256, 256, 0, stream>>>(fw2, pw2, NLAYER, 192, 768);
    }

    embed_kernel<<<(int)((MC + 255) / 256), 256, 0, stream>>>(tok, lens, emb, xb);

    for (int l = 0; l < NLAYER; l++) {
        gemm_mfma<GM_QKV, 576, 192, 1, 64><<<9 * 256, 256, 0, stream>>>(
            xb, pwqkv + (size_t)l * 3 * NC * NC, bqkv + (size_t)l * 3 * NC, lens,
            nullptr, qb, kb, vb);
        attn_mfma<<<dim3(NB * NHEAD, 8), 256, 0, stream>>>(
            qb, kb, vb, relk + (size_t)l * (2 * NW + 1) * NDH,
            relv + (size_t)l * (2 * NW + 1) * NDH, lens, ob);
        gemm_ln<192, 1, false, 64, false><<<512, 512, 0, stream>>>(
            ob, pwo + (size_t)l * NC * NC, bo + (size_t)l * NC, lens,
            ln1g + (size_t)l * NC, ln1b + (size_t)l * NC, xb, nullptr);
        gemm_mfma<GM_CONV1, 768, 192, 3, 64><<<12 * 256, 256, 0, stream>>>(
            xb, pw1 + (size_t)l * 3 * NDFF * NC, fb1 + (size_t)l * NDFF, lens,
            nullptr, hB, nullptr, nullptr);
        if (l < NLAYER - 1) {
            gemm_ln<768, 3, true, 64, false><<<512, 512, 0, stream>>>(
                hB, pw2 + (size_t)l * 3 * NC * NDFF, fb2 + (size_t)l * NC, lens,
                ln2g + (size_t)l * NC, ln2b + (size_t)l * NC, xb, nullptr);
        } else {
            gemm_ln<768, 3, true, 64, true><<<512, 512, 0, stream>>>(
                hB, pw2 + (size_t)l * 3 * NC * NDFF, fb2 + (size_t)l * NC, lens,
                ln2g + (size_t)l * NC, ln2b + (size_t)l * NC, xb, out);
        }
    }

    gemm_mfma<GM_PROJ, 384, 192, 1, 64><<<6 * 256, 256, 0, stream>>>(
        xb, pproj, pb, lens, out, nullptr, nullptr, nullptr);
    mask_kernel<<<(NB * NT + 255) / 256, 256, 0, stream>>>(lens, out + 3 * MC);
}

// Round 19
// 1288.784 us; speedup vs baseline: 1.0873x; 1.0873x over previous
//
#include <hip/hip_runtime.h>
#include <hip/hip_bf16.h>

typedef __hip_bfloat16 bf16;
typedef __attribute__((ext_vector_type(8))) short short8;
typedef __attribute__((ext_vector_type(4))) float f32x4;

#define NB 64
#define NT 512
#define NC 192
#define NHEAD 2
#define NDH 96
#define NLAYER 6
#define NDFF 768
#define NW 4

constexpr int MROWS = NB * NT;            // 32768
constexpr size_t MC = (size_t)MROWS * NC; // 6291456
constexpr size_t MCB = MC * 4;
// 1/sqrt(96) * log2(e): folded into stored q so QK^T and rel-K land in exp2 domain
constexpr float QSC = 0.10206207261596575f * 1.4426950408889634f;

__device__ __forceinline__ float us2f(unsigned short x) { return __uint_as_float((unsigned)x << 16); }
__device__ __forceinline__ unsigned short f2b(float f) {
    bf16 h = __float2bfloat16(f);
    return *reinterpret_cast<unsigned short*>(&h);
}

// ---------------- weight conversion: pack into MFMA B-fragment tiles ----------------
__global__ __launch_bounds__(256) void cvt_frag_plain(const float* __restrict__ s, bf16* __restrict__ d,
                                                      int L, int N, int K) {
    int i = blockIdx.x * 256 + threadIdx.x;
    int total = L * (N / 16) * (K / 32) * 64;
    if (i >= total) return;
    int lane = i & 63;
    int tile = i >> 6;
    int nbk = K / 32;
    int kb = tile % nbk;
    int rest = tile / nbk;
    int nb = rest % (N / 16);
    int l = rest / (N / 16);
    int li = lane & 15, g = lane >> 4;
    const float* src = s + ((size_t)l * N + nb * 16 + li) * K + kb * 32 + g * 8;
    bf16* dst = d + (size_t)i * 8;
#pragma unroll
    for (int u = 0; u < 8; u++) dst[u] = __float2bfloat16(src[u]);
}
// conv: W[L][N][C][3] -> [L][3][N/16][C/32][64][8]
__global__ __launch_bounds__(256) void cvt_frag_conv(const float* __restrict__ s, bf16* __restrict__ d,
                                                     int L, int N, int C) {
    int i = blockIdx.x * 256 + threadIdx.x;
    int total = L * 3 * (N / 16) * (C / 32) * 64;
    if (i >= total) return;
    int lane = i & 63;
    int tile = i >> 6;
    int nbk = C / 32;
    int kb = tile % nbk;
    int rest = tile / nbk;
    int nb = rest % (N / 16);
    int rest2 = rest / (N / 16);
    int dk = rest2 % 3;
    int l = rest2 / 3;
    int li = lane & 15, g = lane >> 4;
    const float* src = s + (((size_t)l * N + nb * 16 + li) * C + kb * 32 + g * 8) * 3 + dk;
    bf16* dst = d + (size_t)i * 8;
#pragma unroll
    for (int u = 0; u < 8; u++) dst[u] = __float2bfloat16(src[u * 3]);
}

// ---------------- embedding (bf16 residual only) ----------------
__global__ __launch_bounds__(256) void embed_kernel(const int* __restrict__ tok,
                                                    const int* __restrict__ lens,
                                                    const float* __restrict__ emb,
                                                    bf16* __restrict__ xb) {
    int idx = blockIdx.x * 256 + threadIdx.x;
    if (idx >= (int)MC) return;
    int c = idx % NC;
    int m = idx / NC;
    int t = m % NT, b = m / NT;
    float v = emb[tok[m] * NC + c] * 13.856406460551018f; // sqrt(192)
    if (t >= lens[b]) v = 0.f;
    xb[idx] = __float2bfloat16(v);
}

// ---------------- plain MFMA GEMM (QKV / CONV1 / PROJ), frag-packed B from global ----------------
// 1-D grid (NBX*256), XCD-swizzled: all n-blocks of one m-panel land on the same XCD
// (bx=(d%(NBX*8))>>3, by=(d/(NBX*8))*8+(d&7); bijective since 256 % 8 == 0).
enum GMode { GM_QKV = 0, GM_CONV1 = 2, GM_PROJ = 4 };

template <int MODE, int NTOT, int KC, int TAPS, int BN>
__global__ __launch_bounds__(256) void gemm_mfma(const bf16* __restrict__ A,
                                                 const bf16* __restrict__ W,
                                                 const float* __restrict__ bias,
                                                 const int* __restrict__ lens,
                                                 float* __restrict__ of,
                                                 bf16* __restrict__ ob1,
                                                 bf16* __restrict__ ob2,
                                                 bf16* __restrict__ ob3) {
    constexpr int RA = (TAPS == 3) ? 130 : 128;
    constexpr int NBN = NTOT / 16;
    constexpr int NBK = KC / 32;
    constexpr int NSUB = BN / 16;
    constexpr int NBX = NTOT / BN;
    __shared__ unsigned short As[RA * 40];
    const int tid = threadIdx.x;
    const int w = tid >> 6, lane = tid & 63;
    const int g = lane >> 4, li = lane & 15;
    const int d = blockIdx.x;
    const int bx = (d % (NBX * 8)) >> 3;
    const int by = ((d / (NBX * 8)) << 3) + (d & 7);
    const int n0 = bx * BN;
    const int m0 = by * 128;
    const int b = m0 >> 9, t0 = m0 & 511;
    const int len = lens[b];
    const int nbBase = n0 >> 4;
    const unsigned short* Au = (const unsigned short*)A;
    const unsigned short* Wu = (const unsigned short*)W;

    f32x4 acc[2][NSUB];
#pragma unroll
    for (int a = 0; a < 2; a++)
#pragma unroll
        for (int s = 0; s < NSUB; s++) acc[a][s] = (f32x4){0.f, 0.f, 0.f, 0.f};

#pragma unroll 1
    for (int k0 = 0; k0 < KC; k0 += 32) {
        const int kb = k0 >> 5;
        __syncthreads();
        for (int c = tid; c < RA * 2; c += 256) {
            int i = c >> 1, hf = (c & 1) * 16;
            int t = t0 + i - (TAPS == 3 ? 1 : 0);
            bool valid = (t >= 0) && (t < NT);
            if constexpr (MODE == GM_CONV1) valid = valid && (t < len);
            short8 v0{}, v1{};
            if (valid) {
                const unsigned short* src = Au + ((size_t)(b * NT + t) * KC + k0 + hf);
                v0 = *(const short8*)src;
                v1 = *(const short8*)(src + 8);
            }
            *(short8*)&As[i * 40 + hf] = v0;
            *(short8*)&As[i * 40 + hf + 8] = v1;
        }
        __syncthreads();
#pragma unroll
        for (int dk = 0; dk < TAPS; dk++) {
            short8 af0 = *(const short8*)&As[(w * 32 + li + dk) * 40 + g * 8];
            short8 af1 = *(const short8*)&As[(w * 32 + 16 + li + dk) * 40 + g * 8];
#pragma unroll
            for (int sub = 0; sub < NSUB; sub++) {
                short8 bfr = *(const short8*)(Wu +
                    ((((size_t)(dk * NBN + nbBase + sub)) * NBK + kb) << 9) + (lane << 3));
                acc[0][sub] = __builtin_amdgcn_mfma_f32_16x16x32_bf16(af0, bfr, acc[0][sub], 0, 0, 0);
                acc[1][sub] = __builtin_amdgcn_mfma_f32_16x16x32_bf16(af1, bfr, acc[1][sub], 0, 0, 0);
            }
        }
    }

#pragma unroll
    for (int sub = 0; sub < NSUB; sub++) {
        int n = n0 + sub * 16 + li;
        float bv = bias[n];
#pragma unroll
        for (int a = 0; a < 2; a++) {
#pragma unroll
            for (int rr = 0; rr < 4; rr++) {
                int t = t0 + w * 32 + a * 16 + g * 4 + rr;
                size_t m = (size_t)(b * NT + t);
                float vv = acc[a][sub][rr] + bv;
                if constexpr (MODE == GM_QKV) {
                    int iw = n / NC;
                    int cc = n - iw * NC;
                    int hh = cc >= NDH ? 1 : 0;
                    int dch = cc - hh * NDH;
                    int bh = b * NHEAD + hh;
                    if (iw == 0) ob1[((size_t)bh * NT + t) * NDH + dch] = __float2bfloat16(vv * QSC);
                    else if (iw == 1) ob2[((size_t)bh * NT + t) * NDH + dch] = __float2bfloat16(vv);
                    else ob3[((size_t)bh * NDH + dch) * NT + t] = __float2bfloat16(vv); // V^T
                } else if constexpr (MODE == GM_CONV1) {
                    vv = vv > 0.f ? vv : 0.f;
                    if (t >= len) vv = 0.f;
                    ob1[m * NDFF + n] = __float2bfloat16(vv);
                } else { // GM_PROJ
                    if (t >= len) vv = 0.f;
                    int half = n >= 192 ? 1 : 0;
                    int cc = n - half * 192;
                    of[(size_t)(half + 1) * MC + ((size_t)b * NC + cc) * NT + t] = vv;
                }
            }
        }
    }
}

// ---------------- fused GEMM + residual + LayerNorm (OPROJ / CONV2), bf16 residual ----------------
// FINAL: additionally writes the masked transposed f32 x to `of` (fuses xpose_kernel).
template <int KC, int TAPS, bool MASKY, int BM, bool FINAL>
__global__ __launch_bounds__(512, 4) void gemm_ln(const bf16* __restrict__ A,
                                                  const bf16* __restrict__ W,
                                                  const float* __restrict__ bias,
                                                  const int* __restrict__ lens,
                                                  const float* __restrict__ lng,
                                                  const float* __restrict__ lnb,
                                                  bf16* __restrict__ xb,
                                                  float* __restrict__ of) {
    constexpr int RA = BM + ((TAPS == 3) ? 2 : 0);
    constexpr int NSTEP = KC / 32;
    constexpr int NBN = 12; // 192/16
    constexpr int NBK = KC / 32;
    constexpr int AR = BM / 32;
    __shared__ unsigned short As[RA * 40];
    __shared__ float rsm[BM][4];
    __shared__ float rsq[BM][4];
    const int tid = threadIdx.x;
    const int lane = tid & 63;
    const int g = lane >> 4, li = lane & 15;
    const int w = tid >> 6;
    const int wr = w & 1, wc = w >> 1;
    const int m0 = blockIdx.x * BM;
    const int b = m0 >> 9, t0 = m0 & 511;
    const int len = lens[b];
    const unsigned short* Au = (const unsigned short*)A;
    const unsigned short* Wu = (const unsigned short*)W;
    unsigned short* Xu = (unsigned short*)xb;

    const int ai = tid >> 1, ahf = (tid & 1) * 16;
    const int at = t0 + ai - (TAPS == 3 ? 1 : 0);
    const bool aon = (tid < RA * 2);
    const bool avalid = aon && (at >= 0) && (at < NT);

    short8 ra0{}, ra1{};
    short8 bcur[TAPS][3], bnxt[TAPS][3];

    f32x4 acc[AR][3];
#pragma unroll
    for (int ar = 0; ar < AR; ar++)
#pragma unroll
        for (int sub = 0; sub < 3; sub++) acc[ar][sub] = (f32x4){0.f, 0.f, 0.f, 0.f};

    if (avalid) {
        const unsigned short* src = Au + ((size_t)(b * NT + at) * KC + 0 + ahf);
        ra0 = *(const short8*)src;
        ra1 = *(const short8*)(src + 8);
    }
#pragma unroll
    for (int dk = 0; dk < TAPS; dk++)
#pragma unroll
        for (int sub = 0; sub < 3; sub++)
            bcur[dk][sub] = *(const short8*)(Wu +
                ((((size_t)(dk * NBN + wc * 3 + sub)) * NBK) << 9) + (lane << 3));
    if (aon) {
        short8 z{};
        *(short8*)&As[ai * 40 + ahf] = avalid ? ra0 : z;
        *(short8*)&As[ai * 40 + ahf + 8] = avalid ? ra1 : z;
    }

#pragma unroll 1
    for (int s = 0; s < NSTEP; s++) {
        __syncthreads();
        if (s + 1 < NSTEP) {
            int k0 = (s + 1) * 32;
            if (avalid) {
                const unsigned short* src = Au + ((size_t)(b * NT + at) * KC + k0 + ahf);
                ra0 = *(const short8*)src;
                ra1 = *(const short8*)(src + 8);
            }
#pragma unroll
            for (int dk = 0; dk < TAPS; dk++)
#pragma unroll
                for (int sub = 0; sub < 3; sub++)
                    bnxt[dk][sub] = *(const short8*)(Wu +
                        ((((size_t)(dk * NBN + wc * 3 + sub)) * NBK + (s + 1)) << 9) + (lane << 3));
        }
#pragma unroll
        for (int dk = 0; dk < TAPS; dk++) {
            short8 af[AR];
#pragma unroll
            for (int ar = 0; ar < AR; ar++)
                af[ar] = *(const short8*)&As[(wr * (BM / 2) + ar * 16 + li + dk) * 40 + g * 8];
#pragma unroll
            for (int sub = 0; sub < 3; sub++) {
#pragma unroll
                for (int ar = 0; ar < AR; ar++)
                    acc[ar][sub] = __builtin_amdgcn_mfma_f32_16x16x32_bf16(af[ar], bcur[dk][sub], acc[ar][sub], 0, 0, 0);
            }
        }
        __syncthreads();
        if (s + 1 < NSTEP) {
            if (aon) {
                short8 z{};
                *(short8*)&As[ai * 40 + ahf] = avalid ? ra0 : z;
                *(short8*)&As[ai * 40 + ahf + 8] = avalid ? ra1 : z;
            }
#pragma unroll
            for (int dk = 0; dk < TAPS; dk++)
#pragma unroll
                for (int sub = 0; sub < 3; sub++) bcur[dk][sub] = bnxt[dk][sub];
        }
    }

    float biasv[3], gv[3], bbv[3];
#pragma unroll
    for (int sub = 0; sub < 3; sub++) {
        int n = wc * 48 + sub * 16 + li;
        biasv[sub] = bias[n];
        gv[sub] = lng[n];
        bbv[sub] = lnb[n];
    }
    float psm[AR][4], psq[AR][4];
#pragma unroll
    for (int ar = 0; ar < AR; ar++) {
#pragma unroll
        for (int rr = 0; rr < 4; rr++) {
            int r = wr * (BM / 2) + ar * 16 + 4 * g + rr;
            int t = t0 + r;
            size_t m = (size_t)(b * NT + t);
            float sm = 0.f, sq = 0.f;
#pragma unroll
            for (int sub = 0; sub < 3; sub++) {
                int n = wc * 48 + sub * 16 + li;
                float y = acc[ar][sub][rr] + biasv[sub];
                if (MASKY && t >= len) y = 0.f;
                float rres = y + us2f(Xu[m * NC + n]);
                acc[ar][sub][rr] = rres;
                sm += rres;
                sq += rres * rres;
            }
            psm[ar][rr] = sm;
            psq[ar][rr] = sq;
        }
    }
#pragma unroll
    for (int off = 1; off < 16; off <<= 1) {
#pragma unroll
        for (int ar = 0; ar < AR; ar++)
#pragma unroll
            for (int rr = 0; rr < 4; rr++) {
                psm[ar][rr] += __shfl_xor(psm[ar][rr], off);
                psq[ar][rr] += __shfl_xor(psq[ar][rr], off);
            }
    }
    if (li == 0) {
#pragma unroll
        for (int ar = 0; ar < AR; ar++)
#pragma unroll
            for (int rr = 0; rr < 4; rr++) {
                int r = wr * (BM / 2) + ar * 16 + 4 * g + rr;
                rsm[r][wc] = psm[ar][rr];
                rsq[r][wc] = psq[ar][rr];
            }
    }
    __syncthreads();
#pragma unroll
    for (int ar = 0; ar < AR; ar++) {
#pragma unroll
        for (int rr = 0; rr < 4; rr++) {
            int r = wr * (BM / 2) + ar * 16 + 4 * g + rr;
            int t = t0 + r;
            size_t m = (size_t)(b * NT + t);
            float sm = rsm[r][0] + rsm[r][1] + rsm[r][2] + rsm[r][3];
            float sq = rsq[r][0] + rsq[r][1] + rsq[r][2] + rsq[r][3];
            float mu = sm * (1.f / NC);
            float var = fmaxf(sq * (1.f / NC) - mu * mu, 0.f);
            float rs = rsqrtf(var + 1e-5f);
#pragma unroll
            for (int sub = 0; sub < 3; sub++) {
                int n = wc * 48 + sub * 16 + li;
                float o = (acc[ar][sub][rr] - mu) * rs * gv[sub] + bbv[sub];
                Xu[m * NC + n] = f2b(o);
                if (FINAL) of[((size_t)b * NC + n) * NT + t] = (t < len) ? o : 0.f;
            }
        }
    }
}

// ---------------- MFMA flash attention v7: ones-column row-sum, lazy rmax reduce ----------------
__global__ __launch_bounds__(256, 4) void attn_mfma(const bf16* __restrict__ q,
                                                    const bf16* __restrict__ k,
                                                    const bf16* __restrict__ v,
                                                    const float* __restrict__ relk,
                                                    const float* __restrict__ relv,
                                                    const int* __restrict__ lens,
                                                    bf16* __restrict__ o) {
    __shared__ __align__(16) char pool[40448];
    unsigned short* Kt = (unsigned short*)pool;              // [64][104]
    unsigned short* Vt = (unsigned short*)(pool + 13312);    // [96][72]
    unsigned short* Pt = (unsigned short*)(pool + 27136);    // [4][16][72]
    unsigned short* Pb = (unsigned short*)(pool + 36352);    // [4][16][32]
    unsigned short* Qt = (unsigned short*)pool;              // prologue alias [64][104]
    unsigned short* Rk = (unsigned short*)(pool + 13312);    // prologue alias [16][104]

    const int bh = blockIdx.x, qt = blockIdx.y;
    const int b = bh >> 1, h = bh & 1;
    const int q0 = qt * 64;
    const int tid = threadIdx.x;
    const int w = tid >> 6, lane = tid & 63;
    const int g = lane >> 4, li = lane & 15;
    const int len = lens[b];
    const bool anymask = (len < NT);

    const unsigned short* qg = (const unsigned short*)q + (size_t)bh * NT * NDH;
    const unsigned short* kg = (const unsigned short*)k + (size_t)bh * NT * NDH;
    const unsigned short* vg = (const unsigned short*)v + (size_t)bh * NDH * NT; // V^T [96][512]

    // ---- prologue ----
    for (int c = tid; c < 64 * 12; c += 256) {
        int r = c / 12, seg = (c % 12) * 8;
        *(short8*)&Qt[r * 104 + seg] = *(const short8*)(qg + (size_t)(q0 + r) * NDH + seg);
    }
    for (int c = tid; c < 16 * 96; c += 256) {
        int dd = c / 96, d = c - (c / 96) * 96;
        Rk[dd * 104 + d] = (dd < 9) ? f2b(relk[dd * 96 + d]) : (unsigned short)0;
    }
    for (int c = tid; c < 4 * 16 * 32; c += 256) Pb[c] = 0;
    __syncthreads();

    // racc[rr] at lane (g,li) = Rt[4g+rr][li]  (q already scaled by QSC -> exp2 domain)
    f32x4 racc = (f32x4){0.f, 0.f, 0.f, 0.f};
    short8 qf[3];
#pragma unroll
    for (int kk = 0; kk < 3; kk++) {
        qf[kk] = *(const short8*)&Qt[(w * 16 + li) * 104 + kk * 32 + g * 8];
        short8 bfr = *(const short8*)&Rk[li * 104 + kk * 32 + g * 8];
        racc = __builtin_amdgcn_mfma_f32_16x16x32_bf16(qf[kk], bfr, racc, 0, 0, 0);
    }
    short8 rvf[6];
#pragma unroll
    for (int ds = 0; ds < 6; ds++) {
#pragma unroll
        for (int i = 0; i < 8; i++) {
            int j = g * 8 + i;
            int d = ds * 16 + li;
            unsigned short u = (j < 9) ? f2b(relv[j * 96 + d]) : (unsigned short)0;
            rvf[ds][i] = (short)u;
        }
    }
    // ones-column B fragment: B[k][0]=1 -> Oa[6] accumulates row sums of P
    short8 bones;
#pragma unroll
    for (int i = 0; i < 8; i++) bones[i] = (li == 0) ? (short)0x3F80 : (short)0;
    __syncthreads();

    float m_run[4];
    f32x4 Oa[7];
#pragma unroll
    for (int rr = 0; rr < 4; rr++) m_run[rr] = -1e30f;
#pragma unroll
    for (int ds = 0; ds < 7; ds++) Oa[ds] = (f32x4){0.f, 0.f, 0.f, 0.f};

    const int wrow0 = q0 + w * 16; // wave's first q-row

    for (int s0 = 0; s0 < NT; s0 += 64) {
        for (int c = tid; c < 64 * 12; c += 256) {
            int ss = c / 12, seg = (c % 12) * 8;
            *(short8*)&Kt[ss * 104 + seg] = *(const short8*)(kg + (size_t)(s0 + ss) * NDH + seg);
        }
        for (int c = tid; c < 96 * 8; c += 256) {
            int d = c >> 3, seg = (c & 7) * 8;
            *(short8*)&Vt[d * 72 + seg] = *(const short8*)(vg + (size_t)d * NT + s0 + seg);
        }
        __syncthreads();

        // wave-uniform: does the +/-4 rel band intersect this s-tile for this wave's rows?
        const bool band = (s0 <= wrow0 + 15 + NW) && (s0 + 63 >= wrow0 - NW);

        // ---- S' = (Q*QSC) K^T  (exp2 domain) ----
        f32x4 acc[4];
#pragma unroll
        for (int sub = 0; sub < 4; sub++) acc[sub] = (f32x4){0.f, 0.f, 0.f, 0.f};
        __builtin_amdgcn_s_setprio(1);
#pragma unroll
        for (int kk = 0; kk < 3; kk++) {
#pragma unroll
            for (int sub = 0; sub < 4; sub++) {
                short8 bfr = *(const short8*)&Kt[(sub * 16 + li) * 104 + kk * 32 + g * 8];
                acc[sub] = __builtin_amdgcn_mfma_f32_16x16x32_bf16(qf[kk], bfr, acc[sub], 0, 0, 0);
            }
        }
        __builtin_amdgcn_s_setprio(0);

        // ---- rel-K band (only on intersecting tiles) ----
        if (band) {
#pragma unroll
            for (int sub = 0; sub < 4; sub++) {
#pragma unroll
                for (int rr = 0; rr < 4; rr++) {
                    int scol = s0 + sub * 16 + li;
                    int qrow = wrow0 + 4 * g + rr;
                    int dd = scol - qrow;
                    float rv = __shfl(racc[rr], g * 16 + dd + NW);
                    if (dd >= -NW && dd <= NW) acc[sub][rr] += rv;
                }
            }
        }
        // ---- mask ----
        if (anymask) {
#pragma unroll
            for (int sub = 0; sub < 4; sub++) {
#pragma unroll
                for (int rr = 0; rr < 4; rr++) {
                    int scol = s0 + sub * 16 + li;
                    int qrow = wrow0 + 4 * g + rr;
                    if (scol >= len || qrow >= len) acc[sub][rr] -= 14427.0f; // -10000*log2(e)
                }
            }
        }
        // ---- per-thread row maxima; cross-lane reduce only if rescale needed ----
        float pmr[4];
#pragma unroll
        for (int rr = 0; rr < 4; rr++) {
            pmr[rr] = fmaxf(fmaxf(acc[0][rr], acc[1][rr]), fmaxf(acc[2][rr], acc[3][rr]));
        }
        float growth = fmaxf(fmaxf(pmr[0] - m_run[0], pmr[1] - m_run[1]),
                             fmaxf(pmr[2] - m_run[2], pmr[3] - m_run[3]));
        if (__any(growth > 11.54f)) { // 8 * log2(e)
#pragma unroll
            for (int off = 1; off < 16; off <<= 1)
#pragma unroll
                for (int rr = 0; rr < 4; rr++) pmr[rr] = fmaxf(pmr[rr], __shfl_xor(pmr[rr], off));
#pragma unroll
            for (int rr = 0; rr < 4; rr++) {
                float mn = fmaxf(m_run[rr], pmr[rr]);
                float scf = exp2f(m_run[rr] - mn);
                m_run[rr] = mn;
#pragma unroll
                for (int ds = 0; ds < 7; ds++) Oa[ds][rr] *= scf;
            }
        }
#pragma unroll
        for (int sub = 0; sub < 4; sub++)
#pragma unroll
            for (int rr = 0; rr < 4; rr++)
                acc[sub][rr] = exp2f(acc[sub][rr] - m_run[rr]);

        // ---- P -> LDS (per-wave) ----
#pragma unroll
        for (int sub = 0; sub < 4; sub++)
#pragma unroll
            for (int rr = 0; rr < 4; rr++)
                Pt[w * 1152 + (4 * g + rr) * 72 + sub * 16 + li] = f2b(acc[sub][rr]);

        // ---- O += P V ; Oa[6] += P . ones (row sums) ----
        __builtin_amdgcn_s_setprio(1);
#pragma unroll
        for (int kk = 0; kk < 2; kk++) {
            short8 pa = *(const short8*)&Pt[w * 1152 + li * 72 + kk * 32 + g * 8];
#pragma unroll
            for (int ds = 0; ds < 6; ds++) {
                short8 bv = *(const short8*)&Vt[(ds * 16 + li) * 72 + kk * 32 + g * 8];
                Oa[ds] = __builtin_amdgcn_mfma_f32_16x16x32_bf16(pa, bv, Oa[ds], 0, 0, 0);
            }
            Oa[6] = __builtin_amdgcn_mfma_f32_16x16x32_bf16(pa, bones, Oa[6], 0, 0, 0);
        }
        __builtin_amdgcn_s_setprio(0);

        // ---- rel-V band via MFMA (only on intersecting tiles) ----
        if (band) {
            for (int j = g; j < 9; j += 4) { // r = li, j in {g, g+4, g+8} covers 16x9
                int u = wrow0 + li + j - NW - s0;
                unsigned short pv_ = (u >= 0 && u < 64) ? Pt[w * 1152 + li * 72 + u] : (unsigned short)0;
                Pb[w * 512 + li * 32 + j] = pv_;
            }
            short8 pband = *(const short8*)&Pb[w * 512 + li * 32 + g * 8];
#pragma unroll
            for (int ds = 0; ds < 6; ds++)
                Oa[ds] = __builtin_amdgcn_mfma_f32_16x16x32_bf16(pband, rvf[ds], Oa[ds], 0, 0, 0);
        }
        __syncthreads();
    }

    // l for row 4g+rr lives in Oa[6][rr] at lane g*16 (col 0)
    float invl[4];
#pragma unroll
    for (int rr = 0; rr < 4; rr++) invl[rr] = 1.f / __shfl(Oa[6][rr], lane & 48);
#pragma unroll
    for (int ds = 0; ds < 6; ds++)
#pragma unroll
        for (int rr = 0; rr < 4; rr++) {
            int qrow = wrow0 + 4 * g + rr;
            o[((size_t)(b * NT + qrow)) * NC + h * 96 + ds * 16 + li] =
                __float2bfloat16(Oa[ds][rr] * invl[rr]);
        }
}

__global__ __launch_bounds__(256) void mask_kernel(const int* __restrict__ lens, float* __restrict__ out) {
    int idx = blockIdx.x * 256 + threadIdx.x;
    if (idx >= NB * NT) return;
    int t = idx % NT;
    int b = idx / NT;
    out[idx] = (t < lens[b]) ? 1.f : 0.f;
}

extern "C" void kernel_launch(void* const* d_in, const int* in_sizes, int n_in,
                              void* d_out, int out_size, void* d_ws, size_t ws_size,
                              hipStream_t stream) {
    (void)in_sizes; (void)n_in; (void)out_size; (void)ws_size;
    const int* tok = (const int*)d_in[0];
    const int* lens = (const int*)d_in[1];
    const float* emb = (const float*)d_in[2];
    const float* wqkv = (const float*)d_in[3];
    const float* bqkv = (const float*)d_in[4];
    const float* wo = (const float*)d_in[5];
    const float* bo = (const float*)d_in[6];
    const float* relk = (const float*)d_in[7];
    const float* relv = (const float*)d_in[8];
    const float* ln1g = (const float*)d_in[9];
    const float* ln1b = (const float*)d_in[10];
    const float* ln2g = (const float*)d_in[11];
    const float* ln2b = (const float*)d_in[12];
    const float* fw1 = (const float*)d_in[13];
    const float* fb1 = (const float*)d_in[14];
    const float* fw2 = (const float*)d_in[15];
    const float* fb2 = (const float*)d_in[16];
    const float* pw = (const float*)d_in[17];
    const float* pb = (const float*)d_in[18];
    float* out = (float*)d_out;

    char* wsb = (char*)d_ws;
    bf16* xb = (bf16*)(wsb + 2 * MCB);             // bf16 [M][C] residual carrier
    bf16* qb = (bf16*)(wsb + 2 * MCB + MCB / 2);   // bf16 [BH][T][DH] (scaled by QSC)
    bf16* kb = qb + MC;
    bf16* vb = kb + MC;                            // stored transposed: [BH][DH][T]
    bf16* ob = vb + MC;
    bf16* hB = qb;                                 // alias: bf16 [M][DFF] over qb..ob
    bf16* pwqkv = ob + MC;                         // frag-packed weights
    bf16* pwo = pwqkv + (size_t)NLAYER * 3 * NC * NC;
    bf16* pw1 = pwo + (size_t)NLAYER * NC * NC;
    bf16* pw2 = pw1 + (size_t)NLAYER * 3 * NDFF * NC;
    bf16* pproj = pw2 + (size_t)NLAYER * 3 * NC * NDFF;

    {
        int n1 = NLAYER * 36 * 6 * 64;      // qkv: N=576,K=192
        cvt_frag_plain<<<(n1 + 255) / 256, 256, 0, stream>>>(wqkv, pwqkv, NLAYER, 576, 192);
        int n2 = NLAYER * 12 * 6 * 64;      // wo: N=192,K=192
        cvt_frag_plain<<<(n2 + 255) / 256, 256, 0, stream>>>(wo, pwo, NLAYER, 192, 192);
        int n3 = 1 * 24 * 6 * 64;           // proj: N=384,K=192
        cvt_frag_plain<<<(n3 + 255) / 256, 256, 0, stream>>>(pw, pproj, 1, 384, 192);
        int n4 = NLAYER * 3 * 48 * 6 * 64;  // conv1: N=768,C=192
        cvt_frag_conv<<<(n4 + 255) / 256, 256, 0, stream>>>(fw1, pw1, NLAYER, 768, 192);
        int n5 = NLAYER * 3 * 12 * 24 * 64; // conv2: N=192,C=768
        cvt_frag_conv<<<(n5 + 255) / 256, 256, 0, stream>>>(fw2, pw2, NLAYER, 192, 768);
    }

    embed_kernel<<<(int)((MC + 255) / 256), 256, 0, stream>>>(tok, lens, emb, xb);

    for (int l = 0; l < NLAYER; l++) {
        gemm_mfma<GM_QKV, 576, 192, 1, 64><<<9 * 256, 256, 0, stream>>>(
            xb, pwqkv + (size_t)l * 3 * NC * NC, bqkv + (size_t)l * 3 * NC, lens,
            nullptr, qb, kb, vb);
        attn_mfma<<<dim3(NB * NHEAD, 8), 256, 0, stream>>>(
            qb, kb, vb, relk + (size_t)l * (2 * NW + 1) * NDH,
            relv + (size_t)l * (2 * NW + 1) * NDH, lens, ob);
        gemm_ln<192, 1, false, 64, false><<<512, 512, 0, stream>>>(
            ob, pwo + (size_t)l * NC * NC, bo + (size_t)l * NC, lens,
            ln1g + (size_t)l * NC, ln1b + (size_t)l * NC, xb, nullptr);
        gemm_mfma<GM_CONV1, 768, 192, 3, 64><<<12 * 256, 256, 0, stream>>>(
            xb, pw1 + (size_t)l * 3 * NDFF * NC, fb1 + (size_t)l * NDFF, lens,
            nullptr, hB, nullptr, nullptr);
        if (l < NLAYER - 1) {
            gemm_ln<768, 3, true, 64, false><<<512, 512, 0, stream>>>(
                hB, pw2 + (size_t)l * 3 * NC * NDFF, fb2 + (size_t)l * NC, lens,
                ln2g + (size_t)l * NC, ln2b + (size_t)l * NC, xb, nullptr);
        } else {
            gemm_ln<768, 3, true, 64, true><<<512, 512, 0, stream>>>(
                hB, pw2 + (size_t)l * 3 * NC * NDFF, fb2 + (size_t)l * NC, lens,
                ln2g + (size_t)l * NC, ln2b + (size_t)l * NC, xb, out);
        }
    }

    gemm_mfma<GM_PROJ, 384, 192, 1, 64><<<6 * 256, 256, 0, stream>>>(
        xb, pproj, pb, lens, out, nullptr, nullptr, nullptr);
    mask_kernel<<<(NB * NT + 255) / 256, 256, 0, stream>>>(lens, out + 3 * MC);
}